// Round 9
// baseline (157.351 us; speedup 1.0000x reference)
//
#include <hip/hip_runtime.h>
#include <cmath>

#define FIN 256
#define FQK 256
#define SCALING 0.0625f  // FQK^-0.5 = 1/16
#define ASTRIDE 264      // f16 elems per LDS row: 528 B (b128-aligned, 2-way banks max)
#define NBUCKET 8
#define CHUNK 512        // edges per counting chunk

typedef _Float16 f16_t;
typedef f16_t f16x8 __attribute__((ext_vector_type(8)));
typedef f16_t f16x2 __attribute__((ext_vector_type(2)));
typedef float f32x4 __attribute__((ext_vector_type(4)));

__device__ __forceinline__ f16x8 cvt8h(float4 a, float4 b) {
    f16x8 r;
    r[0] = (f16_t)a.x; r[1] = (f16_t)a.y; r[2] = (f16_t)a.z; r[3] = (f16_t)a.w;
    r[4] = (f16_t)b.x; r[5] = (f16_t)b.y; r[6] = (f16_t)b.z; r[7] = (f16_t)b.w;
    return r;
}

__device__ __forceinline__ float fdot2f(f16x2 a, f16x2 b, float c) {
#if __has_builtin(__builtin_amdgcn_fdot2)
    return __builtin_amdgcn_fdot2(a, b, c, false);
#else
    return c + (float)a[0] * (float)b[0] + (float)a[1] * (float)b[1];
#endif
}

union H16 { uint4 u; f16x2 h[4]; };
__device__ __forceinline__ float dot16(uint4 ya, uint4 xa, float acc) {
    H16 A; A.u = ya;
    H16 X; X.u = xa;
#pragma unroll
    for (int i = 0; i < 4; ++i) acc = fdot2f(A.h[i], X.h[i], acc);
    return acc;
}

// ---------------------------------------------------------------------------
// Kernel A (fused): blocks [0,FIN): MbF swizzled M; [FIN,FIN+segB): seg;
// [FIN+segB, FIN+segB+NC): per-chunk dest-bucket histogram (counts[c][b]).
// ---------------------------------------------------------------------------
__global__ __launch_bounds__(256) void m_seg_count_kernel(const float* __restrict__ W,
                                                          f16_t* __restrict__ MbF,
                                                          const int* __restrict__ src,
                                                          const int* __restrict__ dest,
                                                          int* __restrict__ seg,
                                                          int* __restrict__ counts,
                                                          int N, int E, int segB, int NC,
                                                          int SLICE) {
    __shared__ int cnt8[NBUCKET];
    const int b = blockIdx.x;
    const int t = threadIdx.x;
    if (b < FIN) {
        const int f = b;
        const int k = t;
        const float* __restrict__ Wq = W;
        const float* __restrict__ Wk = W + FQK * FIN;
        float acc = 0.f;
#pragma unroll 8
        for (int c = 0; c < FQK; ++c)
            acc += Wq[c * FIN + f] * Wk[c * FIN + k];
        const int ft  = f >> 4, m16 = f & 15;
        const int kcI = k >> 5, q = (k >> 3) & 3, e = k & 7;
        MbF[(size_t)(((kcI * 16 + ft) * 64 + q * 16 + m16) * 8 + e)] =
            (f16_t)(acc * SCALING);
    } else if (b < FIN + segB) {
        const int n = (b - FIN) * 256 + t;
        if (n > N) return;
        int lo = 0, hi = E;
        while (lo < hi) {
            const int mid = (lo + hi) >> 1;
            if (src[mid] < n) lo = mid + 1; else hi = mid;
        }
        seg[n] = lo;
    } else {
        const int c = b - FIN - segB;               // chunk id
        if (t < NBUCKET) cnt8[t] = 0;
        __syncthreads();
#pragma unroll
        for (int u = 0; u < 2; ++u) {
            const int e = c * CHUNK + u * 256 + t;
            if (e < E) {
                int d = dest[e];
                d = ((unsigned)d < (unsigned)N) ? d : 0;   // replay-poison clamp
                const int bk = min(d / SLICE, NBUCKET - 1);
                atomicAdd(&cnt8[bk], 1);
            }
        }
        __syncthreads();
        if (t < NBUCKET) counts[c * NBUCKET + t] = cnt8[t];
    }
}

// ---------------------------------------------------------------------------
// Kernel B: one block. Exclusive prefix over counts in (bucket-major, chunk)
// order -> cbase[c][b] absolute start; bstart[b] bucket starts; bstart[8]=E.
// ---------------------------------------------------------------------------
__global__ __launch_bounds__(256) void prefix_kernel(const int* __restrict__ counts,
                                                     int* __restrict__ cbase,
                                                     int* __restrict__ bstart,
                                                     int NC, int E) {
    __shared__ int part[256];
    const int t = threadIdx.x;
    const int K = NBUCKET * NC;
    const int per = (K + 255) / 256;
    const int L0 = t * per;

    int s = 0;
    for (int i = 0; i < per; ++i) {
        const int L = L0 + i;
        if (L < K) {
            const int bk = L / NC, c = L % NC;
            s += counts[c * NBUCKET + bk];
        }
    }
    int val = s;
    part[t] = val;
    __syncthreads();
    for (int off = 1; off < 256; off <<= 1) {
        const int add = (t >= off) ? part[t - off] : 0;
        __syncthreads();
        val += add;
        part[t] = val;
        __syncthreads();
    }
    int p = val - s;                                 // exclusive base for this thread
    for (int i = 0; i < per; ++i) {
        const int L = L0 + i;
        if (L < K) {
            const int bk = L / NC, c = L % NC;
            if (c == 0) bstart[bk] = p;
            cbase[c * NBUCKET + bk] = p;
            p += counts[c * NBUCKET + bk];
        }
    }
    if (t == 0) bstart[NBUCKET] = E;
}

// ---------------------------------------------------------------------------
// Kernel C (fused): blocks [0,GB): gemm y/xh (r5-proven); [GB,GB+NC): scatter
// edges into bucketed order: sd2[p]=(src,dest) clamped, perm[p]=e.
// ---------------------------------------------------------------------------
__global__ __launch_bounds__(256) void gemm_scatter_kernel(const float* __restrict__ x,
                                                           const f16_t* __restrict__ MbF,
                                                           f16_t* __restrict__ y,
                                                           f16_t* __restrict__ xh,
                                                           const int* __restrict__ src,
                                                           const int* __restrict__ dest,
                                                           const int* __restrict__ cbase,
                                                           uint2* __restrict__ sd2,
                                                           int* __restrict__ perm,
                                                           int N, int E, int GB, int SLICE) {
    const int t = threadIdx.x;
    if (blockIdx.x >= GB) {
        // ---- scatter chunk
        __shared__ int off8[NBUCKET];
        const int c = blockIdx.x - GB;
        if (t < NBUCKET) off8[t] = cbase[c * NBUCKET + t];
        __syncthreads();
#pragma unroll
        for (int u = 0; u < 2; ++u) {
            const int e = c * CHUNK + u * 256 + t;
            if (e < E) {
                int d = dest[e];
                d = ((unsigned)d < (unsigned)N) ? d : 0;
                int s = src[e];
                s = ((unsigned)s < (unsigned)N) ? s : 0;
                const int bk = min(d / SLICE, NBUCKET - 1);
                const int p  = atomicAdd(&off8[bk], 1);
                if ((unsigned)p < (unsigned)E) {     // paranoia vs poisoned counts
                    sd2[p]  = make_uint2((unsigned)s, (unsigned)d);
                    perm[p] = e;
                }
            }
        }
        return;
    }

    // ---- gemm (r5 structure, unchanged)
    __shared__ f16_t sA[16 * ASTRIDE];
    const int wv   = t >> 6;
    const int lane = t & 63;
    const int q    = lane >> 4;
    const int m16  = lane & 15;
    const int n0   = blockIdx.x * 16;
    const int f0   = wv * 64;

    {
        const int rsub = t >> 5;
        const int col  = (t & 31) * 8;
#pragma unroll
        for (int p = 0; p < 2; ++p) {
            const int r  = p * 8 + rsub;
            const int n  = n0 + r;
            const int nc = n < N ? n : N - 1;
            const float* __restrict__ xp = x + (size_t)nc * FIN + col;
            const float4 a = *(const float4*)(xp);
            const float4 b2 = *(const float4*)(xp + 4);
            const f16x8 v = cvt8h(a, b2);
            *(f16x8*)&sA[r * ASTRIDE + col] = v;
            if (n < N) *(f16x8*)(xh + (size_t)n * FIN + col) = v;
        }
    }
    __syncthreads();

    f32x4 acc[4] = {};
#pragma unroll
    for (int kc = 0; kc < FIN; kc += 32) {
        const f16x8 af = *(const f16x8*)&sA[m16 * ASTRIDE + kc + q * 8];
        const f16_t* __restrict__ bp =
            MbF + (size_t)(((kc >> 5) * 16 + (f0 >> 4)) * 64 + lane) * 8;
#pragma unroll
        for (int ft = 0; ft < 4; ++ft) {
            union { uint4 u; f16x8 v; } bu;
            bu.u = *(const uint4*)(bp + ft * 512);
            acc[ft] = __builtin_amdgcn_mfma_f32_16x16x32_f16(af, bu.v, acc[ft], 0, 0, 0);
        }
    }

    __syncthreads();
#pragma unroll
    for (int ft = 0; ft < 4; ++ft)
#pragma unroll
        for (int r = 0; r < 4; ++r)
            sA[(q * 4 + r) * ASTRIDE + f0 + ft * 16 + m16] = (f16_t)acc[ft][r];
    __syncthreads();

    {
        const int row = t >> 4;
        const int c   = (t & 15) * 16;
        const int n   = n0 + row;
        if (n < N) {
            const uint4 v0 = *(const uint4*)&sA[row * ASTRIDE + c];
            const uint4 v1 = *(const uint4*)&sA[row * ASTRIDE + c + 8];
            *(uint4*)(y + (size_t)n * FIN + c)     = v0;
            *(uint4*)(y + (size_t)n * FIN + c + 8) = v1;
        }
    }
}

// ---------------------------------------------------------------------------
// Kernel D: bucketed edge dot. blockIdx%8 = bucket (round-robin XCD mapping):
// y-gathers stay in a 1.28 MB slice -> XCD-local L2 hits. Edges within a
// bucket keep chunk order (src near-ascending -> xh reads L1/L2-friendly).
// 8-lane groups, coalesced 128B-per-instr layout, 2-deep pipeline.
// Writes exp(dot) to out[perm[p]] (original edge order).
// ---------------------------------------------------------------------------
__global__ __launch_bounds__(256) void edge_dot_kernel(const f16_t* __restrict__ xh,
                                                       const f16_t* __restrict__ y,
                                                       const uint2* __restrict__ sd2,
                                                       const int* __restrict__ perm,
                                                       const int* __restrict__ bstart,
                                                       float* __restrict__ out,
                                                       int N, int E) {
    const int w    = threadIdx.x >> 6;
    const int lane = threadIdx.x & 63;
    const int g    = lane >> 3;    // edge slot 0..7
    const int j    = lane & 7;     // 16B sub-slice of 128B chunk

    const int bk  = blockIdx.x & 7;
    const int wib = (blockIdx.x >> 3) * 4 + w;       // wave index within bucket
    const int nw  = (gridDim.x >> 3) * 4;            // waves per bucket

    int lo = bstart[bk], hi = bstart[bk + 1];
    lo = min(max(lo, 0), E);
    hi = min(max(hi, lo), E);
    const int len = hi - lo;
    if (len <= 0) return;
    const int spanw = ((len + nw - 1) / nw + 7) & ~7;
    const int base  = lo + wib * spanw;
    if (base >= hi) return;
    const int end = min(base + spanw, hi);

#define EISSUE(Y0, Y1, Y2, Y3, X0, X1, X2, X3, pe, valid)                      \
    if (valid) {                                                               \
        const uint2 sd = sd2[pe];                                              \
        const uint4* __restrict__ yr = (const uint4*)(y + (size_t)sd.y * FIN); \
        const uint4* __restrict__ xr = (const uint4*)(xh + (size_t)sd.x * FIN);\
        Y0 = yr[j]; Y1 = yr[8 + j]; Y2 = yr[16 + j]; Y3 = yr[24 + j];          \
        X0 = xr[j]; X1 = xr[8 + j]; X2 = xr[16 + j]; X3 = xr[24 + j];          \
    }

#define ECONSUME(Y0, Y1, Y2, Y3, X0, X1, X2, X3, pe, valid)                    \
    if (valid) {                                                               \
        float a_ = 0.f;                                                        \
        a_ = dot16(Y0, X0, a_);                                                \
        a_ = dot16(Y1, X1, a_);                                                \
        a_ = dot16(Y2, X2, a_);                                                \
        a_ = dot16(Y3, X3, a_);                                                \
        a_ += __shfl_xor(a_, 1, 64);                                           \
        a_ += __shfl_xor(a_, 2, 64);                                           \
        a_ += __shfl_xor(a_, 4, 64);                                           \
        if (j == 0) {                                                          \
            const int oe = perm[pe];                                           \
            if ((unsigned)oe < (unsigned)E) out[oe] = __expf(a_);              \
        }                                                                      \
    }

    uint4 A0, A1, A2, A3, AX0, AX1, AX2, AX3;
    uint4 B0, B1, B2, B3, BX0, BX1, BX2, BX3;

    int  eA = base + g;
    bool vA = eA < end;
    EISSUE(A0, A1, A2, A3, AX0, AX1, AX2, AX3, eA, vA);

    const int nit = (end - base + 7) >> 3;
    for (int it = 0; it < nit; it += 2) {
        const int eB = base + (it + 1) * 8 + g;
        const bool vB = eB < end;
        EISSUE(B0, B1, B2, B3, BX0, BX1, BX2, BX3, eB, vB);
        ECONSUME(A0, A1, A2, A3, AX0, AX1, AX2, AX3, eA, vA);
        eA = base + (it + 2) * 8 + g;
        vA = eA < end;
        EISSUE(A0, A1, A2, A3, AX0, AX1, AX2, AX3, eA, vA);
        ECONSUME(B0, B1, B2, B3, BX0, BX1, BX2, BX3, eB, vB);
    }

#undef EISSUE
#undef ECONSUME
}

// ---------------------------------------------------------------------------
// Kernel E: segment softmax-normalize in place (8 lanes per node).
// ---------------------------------------------------------------------------
__global__ __launch_bounds__(256) void segnorm_kernel(float* __restrict__ out,
                                                      const int* __restrict__ seg,
                                                      int N, int E) {
    const int n = blockIdx.x * 32 + (threadIdx.x >> 3);
    const int j = threadIdx.x & 7;
    if (n >= N) return;

    int s0 = seg[n], s1 = seg[n + 1];
    s0 = min(max(s0, 0), E);
    s1 = min(max(s1, 0), E);
    if (s1 <= s0) return;

    float sum = 0.f;
    for (int i = s0 + j; i < s1; i += 8) sum += out[i];
    sum += __shfl_xor(sum, 1, 64);
    sum += __shfl_xor(sum, 2, 64);
    sum += __shfl_xor(sum, 4, 64);
    const float inv = 1.0f / sum;

    for (int i = s0 + j; i < s1; i += 8) out[i] *= inv;
}

// ---------------------------------------------------------------------------
extern "C" void kernel_launch(void* const* d_in, const int* in_sizes, int n_in,
                              void* d_out, int out_size, void* d_ws, size_t ws_size,
                              hipStream_t stream) {
    const float* x  = (const float*)d_in[0];
    const int*   ei = (const int*)d_in[1];
    const float* W  = (const float*)d_in[2];
    float* out = (float*)d_out;

    const int N = in_sizes[0] / FIN;
    const int E = in_sizes[1] / 2;
    const int SLICE = (N + NBUCKET - 1) / NBUCKET;
    const int NC = (E + CHUNK - 1) / CHUNK;

    // workspace layout (f16 tables first, then 8B-aligned uint2, then ints)
    f16_t* MbF = (f16_t*)d_ws;                           // 256*256 f16
    f16_t* y   = MbF + (size_t)FIN * FIN;                // N*256 f16
    f16_t* xh  = y + (size_t)N * FIN;                    // N*256 f16
    uint2* sd2 = (uint2*)(xh + (size_t)N * FIN);         // E pairs (8B-aligned)
    int*   perm   = (int*)(sd2 + (size_t)E);             // E
    int*   seg    = perm + (size_t)E;                    // N+1
    int*   counts = seg + (size_t)(N + 2);               // NC*8
    int*   cbase  = counts + (size_t)NC * NBUCKET;       // NC*8
    int*   bstart = cbase + (size_t)NC * NBUCKET;        // 9

    const int segB = (N + 256) / 256;
    m_seg_count_kernel<<<FIN + segB + NC, 256, 0, stream>>>(W, MbF, ei, ei + E, seg,
                                                            counts, N, E, segB, NC, SLICE);

    prefix_kernel<<<1, 256, 0, stream>>>(counts, cbase, bstart, NC, E);

    const int GB = (N + 15) / 16;
    gemm_scatter_kernel<<<GB + NC, 256, 0, stream>>>(x, MbF, y, xh, ei, ei + E,
                                                     cbase, sd2, perm, N, E, GB, SLICE);

    edge_dot_kernel<<<2048, 256, 0, stream>>>(xh, y, sd2, perm, bstart, out, N, E);

    segnorm_kernel<<<(N + 31) / 32, 256, 0, stream>>>(out, seg, N, E);
}

// Round 10
// 132.293 us; speedup vs baseline: 1.1894x; 1.1894x over previous
//
#include <hip/hip_runtime.h>
#include <cmath>

#define FIN 256
#define FQK 256
#define SCALING 0.0625f  // FQK^-0.5 = 1/16
#define MAX_SEG 256
#define ASTRIDE 264      // f16 elems per LDS row: 528 B (b128-aligned, 2-way banks max)

typedef _Float16 f16_t;
typedef f16_t f16x8 __attribute__((ext_vector_type(8)));
typedef f16_t f16x2 __attribute__((ext_vector_type(2)));
typedef float f32x4 __attribute__((ext_vector_type(4)));

// fp32 -> fp16x8 (RNE via native cast)
__device__ __forceinline__ f16x8 cvt8h(float4 a, float4 b) {
    f16x8 r;
    r[0] = (f16_t)a.x; r[1] = (f16_t)a.y; r[2] = (f16_t)a.z; r[3] = (f16_t)a.w;
    r[4] = (f16_t)b.x; r[5] = (f16_t)b.y; r[6] = (f16_t)b.z; r[7] = (f16_t)b.w;
    return r;
}

// v_dot2_f32_f16 when available; exact scalar fallback otherwise
__device__ __forceinline__ float fdot2f(f16x2 a, f16x2 b, float c) {
#if __has_builtin(__builtin_amdgcn_fdot2)
    return __builtin_amdgcn_fdot2(a, b, c, false);
#else
    return c + (float)a[0] * (float)b[0] + (float)a[1] * (float)b[1];
#endif
}

union H16 { uint4 u; f16x2 h[4]; };
__device__ __forceinline__ float dot16(uint4 ya, uint4 xa, float acc) {
    H16 A; A.u = ya;
    H16 X; X.u = xa;
#pragma unroll
    for (int i = 0; i < 4; ++i) acc = fdot2f(A.h[i], X.h[i], acc);
    return acc;
}

// ---------------------------------------------------------------------------
// Kernel 1: MbF (B-fragment-swizzled M matrix, fp16), 256 blocks only.
//   M[f][k] = SCALING * sum_c W[c][f] * W[256+c][k]
//   flat = (((k>>5)*16 + (f>>4))*64 + ((k>>3)&3)*16 + (f&15))*8 + (k&7)
// Short critical path: this kernel gates the gemm (seg moved to kernel 2).
// ---------------------------------------------------------------------------
__global__ __launch_bounds__(256) void m_kernel(const float* __restrict__ W,
                                                f16_t* __restrict__ MbF) {
    const int f = blockIdx.x;
    const int k = threadIdx.x;
    const float* __restrict__ Wq = W;              // block-uniform loads
    const float* __restrict__ Wk = W + FQK * FIN;  // coalesced loads
    float acc = 0.f;
#pragma unroll 8
    for (int c = 0; c < FQK; ++c)
        acc += Wq[c * FIN + f] * Wk[c * FIN + k];
    const int ft  = f >> 4, m16 = f & 15;
    const int kcI = k >> 5, q = (k >> 3) & 3, e = k & 7;
    MbF[(size_t)(((kcI * 16 + ft) * 64 + q * 16 + m16) * 8 + e)] =
        (f16_t)(acc * SCALING);
}

// ---------------------------------------------------------------------------
// Kernel 2 (fused): blocks [0,GB): gemm y/xh, 32 rows/block, 2 m-tiles
// (B-fragments register-reused across both m-tiles -> MbF L2 traffic halved,
// 64 MFMA/wave); blocks [GB,GB+segB): seg[n] = lower_bound(src, n).
// ---------------------------------------------------------------------------
__global__ __launch_bounds__(256) void gemm_seg_kernel(const float* __restrict__ x,
                                                       const f16_t* __restrict__ MbF,
                                                       f16_t* __restrict__ y,
                                                       f16_t* __restrict__ xh,
                                                       const int* __restrict__ src,
                                                       int* __restrict__ seg,
                                                       int N, int E, int GB) {
    const int t = threadIdx.x;

    if (blockIdx.x >= GB) {
        // ---- seg binary search (independent of gemm outputs)
        const int n = (blockIdx.x - GB) * 256 + t;
        if (n > N) return;
        int lo = 0, hi = E;
        while (lo < hi) {
            const int mid = (lo + hi) >> 1;
            if (src[mid] < n) lo = mid + 1; else hi = mid;
        }
        seg[n] = lo;
        return;
    }

    __shared__ f16_t sA[32 * ASTRIDE];

    const int wv   = t >> 6;
    const int lane = t & 63;
    const int q    = lane >> 4;    // quad 0..3 -> k-offset q*8
    const int m16  = lane & 15;
    const int n0   = blockIdx.x * 32;
    const int f0   = wv * 64;

    // ---- stage A + xh: pass p -> row p*8 + (t>>5), cols (t&31)*8..+8
    {
        const int rsub = t >> 5;          // 0..7
        const int col  = (t & 31) * 8;
#pragma unroll
        for (int p = 0; p < 4; ++p) {
            const int r  = p * 8 + rsub;
            const int n  = n0 + r;
            const int nc = n < N ? n : N - 1;
            const float* __restrict__ xp = x + (size_t)nc * FIN + col;
            const float4 a = *(const float4*)(xp);
            const float4 b = *(const float4*)(xp + 4);
            const f16x8 v = cvt8h(a, b);
            *(f16x8*)&sA[r * ASTRIDE + col] = v;
            if (n < N) *(f16x8*)(xh + (size_t)n * FIN + col) = v;
        }
    }
    __syncthreads();

    f32x4 acc[2][4] = {};   // [m-tile][f-tile]

#pragma unroll
    for (int kc = 0; kc < FIN; kc += 32) {
        f16x8 afrag[2];
#pragma unroll
        for (int mt = 0; mt < 2; ++mt)
            afrag[mt] = *(const f16x8*)&sA[(mt * 16 + m16) * ASTRIDE + kc + q * 8];

        const f16_t* __restrict__ bp =
            MbF + (size_t)(((kc >> 5) * 16 + (f0 >> 4)) * 64 + lane) * 8;
#pragma unroll
        for (int ft = 0; ft < 4; ++ft) {
            union { uint4 u; f16x8 v; } bu;
            bu.u = *(const uint4*)(bp + ft * 512);
#pragma unroll
            for (int mt = 0; mt < 2; ++mt)
                acc[mt][ft] = __builtin_amdgcn_mfma_f32_16x16x32_f16(afrag[mt], bu.v,
                                                                    acc[mt][ft], 0, 0, 0);
        }
    }

    // ---- epilogue: transpose through LDS for packed stores
    __syncthreads();   // all A-reads done; safe to overwrite sA
#pragma unroll
    for (int mt = 0; mt < 2; ++mt)
#pragma unroll
        for (int ft = 0; ft < 4; ++ft)
#pragma unroll
            for (int r = 0; r < 4; ++r)
                sA[(mt * 16 + q * 4 + r) * ASTRIDE + f0 + ft * 16 + m16] =
                    (f16_t)acc[mt][ft][r];
    __syncthreads();

#pragma unroll
    for (int s = 0; s < 2; ++s) {
        const int row = s * 16 + (t >> 4);   // 0..31
        const int c   = (t & 15) * 16;       // f16-element col
        const int n   = n0 + row;
        if (n < N) {
            const uint4 v0 = *(const uint4*)&sA[row * ASTRIDE + c];
            const uint4 v1 = *(const uint4*)&sA[row * ASTRIDE + c + 8];
            *(uint4*)(y + (size_t)n * FIN + c)     = v0;
            *(uint4*)(y + (size_t)n * FIN + c + 8) = v1;
        }
    }
}

// ---------------------------------------------------------------------------
// Kernel 3: node-centric persistent waves (2048 blocks x 4 waves) — r8
// verbatim (proven 130.9 µs config). 8-lane groups (g=edge slot, j).
// Transaction-coalesced gather: the 8 lanes of a group read 8 CONSECUTIVE
// uint4s per instruction (128 B, 4 lanes/line). 2-deep y-gather pipeline,
// dest indices prefetched one phase ahead. Indices clamped (replay poison).
// ---------------------------------------------------------------------------
__global__ __launch_bounds__(256) void node_edge_kernel(const f16_t* __restrict__ xh,
                                                        const f16_t* __restrict__ y,
                                                        const int* __restrict__ dest,
                                                        const int* __restrict__ seg,
                                                        float* __restrict__ out,
                                                        int N, int E, int nwaves) {
    __shared__ float exlds[4][MAX_SEG];

    const int w    = threadIdx.x >> 6;
    const int lane = threadIdx.x & 63;
    const int g    = lane >> 3;    // edge slot 0..7
    const int j    = lane & 7;     // 16B sub-slice within each 128B chunk

#define DCLAMP(d) ((unsigned)(d) < (unsigned)N ? (d) : 0)

#define GISSUE(B0, B1, B2, B3, dval, valid)                                    \
    if (valid) {                                                               \
        const int d_ = DCLAMP(dval);                                           \
        const uint4* __restrict__ yr = (const uint4*)(y + (size_t)d_ * FIN);   \
        B0 = yr[j]; B1 = yr[8 + j]; B2 = yr[16 + j]; B3 = yr[24 + j];          \
    }

#define CONSUME(B0, B1, B2, B3, idx, valid)                                    \
    if (valid) {                                                               \
        float a_ = 0.f;                                                        \
        a_ = dot16(B0, X0, a_);                                                \
        a_ = dot16(B1, X1, a_);                                                \
        a_ = dot16(B2, X2, a_);                                                \
        a_ = dot16(B3, X3, a_);                                                \
        a_ += __shfl_xor(a_, 1, 64);                                           \
        a_ += __shfl_xor(a_, 2, 64);                                           \
        a_ += __shfl_xor(a_, 4, 64);                                           \
        const float ex = __expf(a_);                                           \
        sum += ex;                                                             \
        if (j == 0 && (idx) < MAX_SEG) exlds[w][idx] = ex;                     \
    }

    for (int n = blockIdx.x * 4 + w; n < N; n += nwaves) {
        int s0 = seg[n], s1 = seg[n + 1];
        s0 = min(max(s0, 0), E);                     // replay-poison clamps
        s1 = min(max(s1, 0), E);
        const int cnt = s1 - s0;
        if (cnt <= 0) continue;

        // xh[n] slices with the SAME mapping as the gather (features match)
        const uint4* __restrict__ xp = (const uint4*)(xh + (size_t)n * FIN);
        const uint4 X0 = xp[j], X1 = xp[8 + j], X2 = xp[16 + j], X3 = xp[24 + j];

        float sum = 0.f;
        const int nit = (cnt + 7) >> 3;

        uint4 A0, A1, A2, A3, B0, B1, B2, B3;

        bool vA = g < cnt;
        int  dA = vA ? dest[s0 + g] : 0;             // idx for stage 0
        GISSUE(A0, A1, A2, A3, dA, vA);
        bool vBn = (8 + g) < cnt;                    // idx for stage 1, a phase early
        int  dB  = vBn ? dest[s0 + 8 + g] : 0;

        for (int it = 0; it < nit; it += 2) {
            const int  iB = (it + 1) * 8 + g;        // stage it+1
            const bool vB = iB < cnt;
            GISSUE(B0, B1, B2, B3, dB, vB);
            const int  iA2 = (it + 2) * 8 + g;       // prefetch idx for stage it+2
            const bool vA2 = iA2 < cnt;
            dA = vA2 ? dest[s0 + iA2] : 0;
            CONSUME(A0, A1, A2, A3, it * 8 + g, vA);
            GISSUE(A0, A1, A2, A3, dA, vA2);
            const int  iB3 = (it + 3) * 8 + g;       // prefetch idx for stage it+3
            const bool vB3 = iB3 < cnt;
            dB = vB3 ? dest[s0 + iB3] : 0;
            CONSUME(B0, B1, B2, B3, iB, vB);
            vA = vA2;
        }

        // 8 groups hold identical partial sums internally; combine groups
        sum += __shfl_xor(sum, 8, 64);
        sum += __shfl_xor(sum, 16, 64);
        sum += __shfl_xor(sum, 32, 64);
        const float inv = 1.0f / sum;

        const int lim = cnt < MAX_SEG ? cnt : MAX_SEG;
        for (int i = lane; i < lim; i += 64)
            out[s0 + i] = exlds[w][i] * inv;
    }

#undef GISSUE
#undef CONSUME
#undef DCLAMP
}

// ---------------------------------------------------------------------------
extern "C" void kernel_launch(void* const* d_in, const int* in_sizes, int n_in,
                              void* d_out, int out_size, void* d_ws, size_t ws_size,
                              hipStream_t stream) {
    const float* x  = (const float*)d_in[0];
    const int*   ei = (const int*)d_in[1];
    const float* W  = (const float*)d_in[2];
    float* out = (float*)d_out;

    const int N = in_sizes[0] / FIN;
    const int E = in_sizes[1] / 2;

    // workspace layout (all fp16 tables 16B-aligned)
    f16_t* MbF = (f16_t*)d_ws;                        // 256*256 fp16 (swizzled)
    f16_t* y   = MbF + (size_t)FIN * FIN;             // N*256 fp16
    f16_t* xh  = y + (size_t)N * FIN;                 // N*256 fp16
    int*   seg = (int*)(xh + (size_t)N * FIN);        // N+1

    m_kernel<<<FIN, 256, 0, stream>>>(W, MbF);

    const int GB   = (N + 31) / 32;                   // 625 gemm blocks
    const int segB = (N + 256) / 256;                 // covers n = 0..N
    gemm_seg_kernel<<<GB + segB, 256, 0, stream>>>(x, MbF, y, xh, ei, seg, N, E, GB);

    const int neBlocks = 2048;                        // 8192 waves
    node_edge_kernel<<<neBlocks, 256, 0, stream>>>(xh, y, ei + E, seg, out,
                                                   N, E, neBlocks * 4);
}